// Round 8
// baseline (378.905 us; speedup 1.0000x reference)
//
#include <hip/hip_runtime.h>
#include <cstdint>
#include <cstddef>

#define NB 4
#define NS 2048
#define NHH 12
#define DH 80      // concatenated head dim (64 text + 16 layout)
#define HT 768
#define HL 192

typedef __bf16 bf16x8 __attribute__((ext_vector_type(8)));
typedef _Float16 f16x8 __attribute__((ext_vector_type(8)));
typedef _Float16 f16x2 __attribute__((ext_vector_type(2)));
typedef float f32x4 __attribute__((ext_vector_type(4)));
typedef float f32x16 __attribute__((ext_vector_type(16)));
typedef unsigned short u16x4 __attribute__((ext_vector_type(4)));

__device__ __forceinline__ unsigned short bfc(float f) {
  __bf16 b = (__bf16)f;
  return __builtin_bit_cast(unsigned short, b);
}
__device__ __forceinline__ unsigned short f16c(float f) {
  _Float16 h = (_Float16)f;
  return __builtin_bit_cast(unsigned short, h);
}

__device__ __forceinline__ float ex2(float x) {
  return __builtin_amdgcn_exp2f(x);   // raw v_exp_f32 (base-2)
}

__device__ __forceinline__ f32x4 mfma_bf16_k32(bf16x8 a, bf16x8 b, f32x4 c) {
  return __builtin_amdgcn_mfma_f32_16x16x32_bf16(a, b, c, 0, 0, 0);
}
__device__ __forceinline__ f32x16 mfma_bf16_32(bf16x8 a, bf16x8 b, f32x16 c) {
  return __builtin_amdgcn_mfma_f32_32x32x16_bf16(a, b, c, 0, 0, 0);
}
__device__ __forceinline__ f32x16 mfma_f16_32(f16x8 a, f16x8 b, f32x16 c) {
  return __builtin_amdgcn_mfma_f32_32x32x16_f16(a, b, c, 0, 0, 0);
}

__device__ __forceinline__ f16x2 pk_f16(float a, float b) {
  return __builtin_bit_cast(f16x2, __builtin_amdgcn_cvt_pkrtz(a, b));
}

// async global->LDS, 16B per lane (LDS dst must be wave-uniform base + lane*16)
__device__ __forceinline__ void gl_lds(const unsigned short* g, unsigned short* l) {
  __builtin_amdgcn_global_load_lds(
      (const __attribute__((address_space(1))) uint32_t*)g,
      (__attribute__((address_space(3))) uint32_t*)l, 16, 0, 0);
}

// ---------------- prep: fp32->bf16 casts + LDS-tiled weight transposes -------
__global__ __launch_bounds__(256) void k_prep(
    const float* __restrict__ hs, const float* __restrict__ li,
    const float* __restrict__ Wq, const float* __restrict__ Wk, const float* __restrict__ Wv,
    const float* __restrict__ lWq, const float* __restrict__ lWk, const float* __restrict__ lWv,
    unsigned short* __restrict__ Xb, unsigned short* __restrict__ Xlb,
    unsigned short* __restrict__ WtQ, unsigned short* __restrict__ WtK,
    unsigned short* __restrict__ WtV, unsigned short* __restrict__ WtLQ,
    unsigned short* __restrict__ WtLK, unsigned short* __restrict__ WtLV) {
  __shared__ float Ts[32][33];
  int blk = blockIdx.x, tid = threadIdx.x;
  if (blk < 7680) {  // casts, 4 floats/thread, coalesced float4
    const float* src; unsigned short* dst; int i;
    if (blk < 6144) { src = hs; dst = Xb;  i = blk * 256 + tid; }
    else            { src = li; dst = Xlb; i = (blk - 6144) * 256 + tid; }
    float4 v = *(const float4*)(src + (size_t)i * 4);
    u16x4 o; o[0] = bfc(v.x); o[1] = bfc(v.y); o[2] = bfc(v.z); o[3] = bfc(v.w);
    *(u16x4*)(dst + (size_t)i * 4) = o;
  } else {           // tiled transpose: wt[n*K+k] = w[k*K+n] (square)
    const float* w; unsigned short* wt; int t, K;
    if (blk < 9408) {
      int b2 = blk - 7680; int m = b2 / 576; t = b2 - m * 576; K = 768;
      w  = (m == 0) ? Wq  : (m == 1) ? Wk  : Wv;
      wt = (m == 0) ? WtQ : (m == 1) ? WtK : WtV;
    } else {
      int b2 = blk - 9408; int m = b2 / 36; t = b2 - m * 36; K = 192;
      w  = (m == 0) ? lWq  : (m == 1) ? lWk  : lWv;
      wt = (m == 0) ? WtLQ : (m == 1) ? WtLK : WtLV;
    }
    int TB = K >> 5;                 // tiles per dim
    int kb = t / TB, nb = t - kb * TB;
    int tx = tid & 31, ty = tid >> 5;
#pragma unroll
    for (int j = 0; j < 4; ++j)
      Ts[ty + j * 8][tx] = w[(size_t)(kb * 32 + ty + j * 8) * K + nb * 32 + tx];
    __syncthreads();
#pragma unroll
    for (int j = 0; j < 4; ++j)
      wt[(size_t)(nb * 32 + ty + j * 8) * K + kb * 32 + tx] = bfc(Ts[tx][ty + j * 8]);
  }
}

// ---------------- fused QKV projection (blockIdx.z = 0:Q 1:K 2:V) -----------
struct ProjArgs {
  const unsigned short* Wt[3];
  const float* bias[3];
  unsigned short* dst[3];
  float scale[3];
  int mode[3];   // 0: q/k bf16 layout [b,h,s,80] (swapped C), 1: v f16 [b,h,80,s]
};

template<int NT>   // BN = NT*16 output cols per block; BM=128, BK=64
__global__ __launch_bounds__(256, 4) void k_proj(
    const unsigned short* __restrict__ Xb, ProjArgs pa,
    int K, int hdshift, int dofs) {
  constexpr int BN = NT * 16;
  __shared__ unsigned short Xs[128 * 72];
  __shared__ unsigned short Ws[BN * 72];
  int z = blockIdx.z;
  const unsigned short* Wt = pa.Wt[z];
  const bool swp = (pa.mode[z] == 0);   // mode 0: C^T orientation (coalesced store)
  int m0 = blockIdx.x * 128, n0 = blockIdx.y * BN;
  int tid = threadIdx.x;
  int lane = tid & 63, wave = tid >> 6, quad = lane >> 4, l16 = lane & 15;

  f32x4 acc[2][NT];
#pragma unroll
  for (int mt = 0; mt < 2; ++mt)
#pragma unroll
    for (int nt = 0; nt < NT; ++nt) {
      acc[mt][nt][0] = 0.f; acc[mt][nt][1] = 0.f;
      acc[mt][nt][2] = 0.f; acc[mt][nt][3] = 0.f;
    }

  for (int kk = 0; kk < K; kk += 64) {
    constexpr int XCH = 128 * 9;   // 16B chunks (9/row: 8 data + 1 pad)
#pragma unroll
    for (int p = 0; p < (XCH + 255) / 256; ++p) {
      int i = p * 256 + tid;
      if (i < XCH) {
        int r = i / 9, c = i - r * 9;
        gl_lds(Xb + (size_t)(m0 + r) * K + kk + (c == 8 ? 0 : c * 8), Xs + i * 8);
      }
    }
    constexpr int WCH = BN * 9;
#pragma unroll
    for (int p = 0; p < (WCH + 255) / 256; ++p) {
      int i = p * 256 + tid;
      if (i < WCH) {
        int r = i / 9, c = i - r * 9;
        gl_lds(Wt + (size_t)(n0 + r) * K + kk + (c == 8 ? 0 : c * 8), Ws + i * 8);
      }
    }
    __syncthreads();

#pragma unroll
    for (int kc = 0; kc < 2; ++kc) {
      bf16x8 x0 = *(const bf16x8*)&Xs[(wave * 32 + l16) * 72 + kc * 32 + quad * 8];
      bf16x8 x1 = *(const bf16x8*)&Xs[(wave * 32 + 16 + l16) * 72 + kc * 32 + quad * 8];
      if (swp) {
#pragma unroll
        for (int nt = 0; nt < NT; ++nt) {
          bf16x8 wf = *(const bf16x8*)&Ws[(nt * 16 + l16) * 72 + kc * 32 + quad * 8];
          acc[0][nt] = mfma_bf16_k32(wf, x0, acc[0][nt]);
          acc[1][nt] = mfma_bf16_k32(wf, x1, acc[1][nt]);
        }
      } else {
#pragma unroll
        for (int nt = 0; nt < NT; ++nt) {
          bf16x8 wf = *(const bf16x8*)&Ws[(nt * 16 + l16) * 72 + kc * 32 + quad * 8];
          acc[0][nt] = mfma_bf16_k32(x0, wf, acc[0][nt]);
          acc[1][nt] = mfma_bf16_k32(x1, wf, acc[1][nt]);
        }
      }
    }
    __syncthreads();
  }

  const float* bias = pa.bias[z];
  unsigned short* dst = pa.dst[z];
  float scale = pa.scale[z];
  int hdm = (1 << hdshift) - 1;
  if (swp) {
    // C^T: lane l16 -> row m (s), quad*4+r -> col n (d). One u16x4 store/tile.
#pragma unroll
    for (int mt = 0; mt < 2; ++mt) {
      int m_l = m0 + wave * 32 + mt * 16 + l16;
      int b = m_l >> 11, s = m_l & (NS - 1);
      size_t rowbase = (size_t)b * NHH * NS * DH + (size_t)s * DH + dofs;
#pragma unroll
      for (int nt = 0; nt < NT; ++nt) {
        int dl = nt * 16 + quad * 4;
        int n = n0 + dl;
        f32x4 b4 = *(const f32x4*)(bias + n);
        int h = n >> hdshift, d = n & hdm;
        u16x4 pk;
#pragma unroll
        for (int r = 0; r < 4; ++r) pk[r] = bfc((acc[mt][nt][r] + b4[r]) * scale);
        *(u16x4*)(dst + rowbase + (size_t)h * NS * DH + d) = pk;
      }
    }
  } else {
    // V: lane l16 -> col n (d), quad*4+r -> row m (s). u16x4 along s.
#pragma unroll
    for (int mt = 0; mt < 2; ++mt) {
#pragma unroll
      for (int nt = 0; nt < NT; ++nt) {
        int n = n0 + nt * 16 + l16;
        float bv = bias[n];
        int mbase = m0 + wave * 32 + mt * 16 + quad * 4;
        int h = n >> hdshift, d = n & hdm;
        int b = mbase >> 11, s = mbase & (NS - 1);
        u16x4 pk;
#pragma unroll
        for (int r = 0; r < 4; ++r) pk[r] = f16c((acc[mt][nt][r] + bv) * scale);
        *(u16x4*)(dst + ((size_t)(b * NHH + h) * DH + dofs + d) * NS + s) = pk;
      }
    }
  }
}

// ---------------- fused two-stream attention, 32x32 MFMA, 64q/wave ----------
// Q',K' [b,h,s,80] bf16 pre-scaled (Q carries log2e); V' [b,h,80,s] f16.
// 128 queries/block, 2 waves x 64 queries (2 col-tiles), 64-key tiles,
// double-buffered staging, one barrier/tile. K stored with key bits2<->3
// swapped so Sc^T C-regs 8p..8p+7 ARE the PV B-frag for key-step 2t+p.
// K/V LDS frags shared across each wave's 2 query tiles (halves LDS reads).
// Rowsum via ones-row 80 of V'. Grid (48,16): head-major -> XCD L2 locality.
__global__ __launch_bounds__(128, 2) void k_attn(
    const unsigned short* __restrict__ Qg, const unsigned short* __restrict__ Kg,
    const unsigned short* __restrict__ Vg,
    float* __restrict__ outT, float* __restrict__ outL) {
  __shared__ unsigned short KT[2][64 * 88];   // stride 88 shorts (11 chunks/row)
  __shared__ unsigned short VT[2][96 * 72];   // stride 72 shorts (9 chunks/row)

  int tid = threadIdx.x;
  int lane = tid & 63, w = tid >> 6, h = lane >> 5, l32 = lane & 31;
  int bh = blockIdx.x, qb = blockIdx.y;
  int bb = bh / NHH, hh = bh - bb * NHH;
  int q0 = qb * 128;

  const unsigned short* kg0 = Kg + (size_t)bh * NS * DH;
  const unsigned short* vg0 = Vg + (size_t)bh * DH * NS;

  // ones row 80 (f16 1.0) + zero rows 81..95, both buffers
  for (int i = tid; i < 2304; i += 128) {
    int b = i / 1152, j = i - b * 1152;
    VT[b][80 * 72 + j] = (j < 72) ? (unsigned short)0x3C00 : (unsigned short)0;
  }

  // Q B-frags: qf[qt][kc][j] = Q[q0 + w*64 + qt*32 + l32][kc*16 + 8h + j]
  bf16x8 qf[2][5];
#pragma unroll
  for (int qt = 0; qt < 2; ++qt) {
    const unsigned short* qrow =
        Qg + ((size_t)bh * NS + q0 + w * 64 + qt * 32 + l32) * DH;
#pragma unroll
    for (int kc = 0; kc < 5; ++kc)
      qf[qt][kc] = *(const bf16x8*)(qrow + kc * 16 + h * 8);
  }

  f32x16 o[2][3];
#pragma unroll
  for (int qt = 0; qt < 2; ++qt)
#pragma unroll
    for (int vt = 0; vt < 3; ++vt)
#pragma unroll
      for (int r = 0; r < 16; ++r) o[qt][vt][r] = 0.f;

  auto stage = [&](int buf, int kt) {
    const unsigned short* kb = kg0 + (size_t)kt * 64 * DH;
    unsigned short* dk = &KT[buf][0];
#pragma unroll
    for (int p = 0; p < 6; ++p) {           // 64 rows x 11 chunks = 704
      int i = p * 128 + tid;
      if (i < 704) {
        int r = i / 11, c = i - r * 11;
        int rs = ((((r >> 2) ^ (r >> 3)) & 1) ? (r ^ 12) : r);  // swap key bits 2,3
        gl_lds(kb + (size_t)rs * DH + (c == 10 ? 0 : c * 8), dk + i * 8);
      }
    }
    int k0 = kt * 64;
    unsigned short* dv = &VT[buf][0];
#pragma unroll
    for (int p = 0; p < 6; ++p) {           // 80 rows x 9 chunks = 720
      int i = p * 128 + tid;
      if (i < 720) {
        int r = i / 9, c = i - r * 9;
        gl_lds((c == 8) ? vg0 : (vg0 + (size_t)r * NS + k0 + c * 8), dv + i * 8);
      }
    }
  };

  stage(0, 0);

  for (int kt = 0; kt < 32; ++kt) {
    int cur = kt & 1;
    __syncthreads();                 // drains tile-kt loads; frees other buffer
    if (kt + 1 < 32) stage(cur ^ 1, kt + 1);

    const unsigned short* Kc = &KT[cur][0];
    const unsigned short* Vc = &VT[cur][0];

    // Sc^T: 2 key-tiles x 2 query-tiles, K-dim 80 = 5 steps of 16.
    // K A-frag shared across the 2 query tiles.
    f32x16 st[2][2];
#pragma unroll
    for (int qt = 0; qt < 2; ++qt)
#pragma unroll
      for (int t = 0; t < 2; ++t)
#pragma unroll
        for (int r = 0; r < 16; ++r) st[qt][t][r] = 0.f;

#pragma unroll
    for (int kc = 0; kc < 5; ++kc) {
#pragma unroll
      for (int t = 0; t < 2; ++t) {
        bf16x8 a = *(const bf16x8*)&Kc[(t * 32 + l32) * 88 + kc * 16 + h * 8];
        st[0][t] = mfma_bf16_32(a, qf[0][kc], st[0][t]);
        st[1][t] = mfma_bf16_32(a, qf[1][kc], st[1][t]);
      }
    }

    // exp2 + pack (Q pre-scaled by log2e); V A-frag shared across query tiles
#pragma unroll
    for (int t = 0; t < 2; ++t) {
#pragma unroll
      for (int p = 0; p < 2; ++p) {
        f16x8 pv[2];
#pragma unroll
        for (int qt = 0; qt < 2; ++qt) {
          union { f16x8 v; f16x2 h2[4]; } u;
#pragma unroll
          for (int j2 = 0; j2 < 4; ++j2)
            u.h2[j2] = pk_f16(ex2(st[qt][t][8 * p + 2 * j2]),
                              ex2(st[qt][t][8 * p + 2 * j2 + 1]));
          pv[qt] = u.v;
        }
        int s = 2 * t + p;
#pragma unroll
        for (int vt = 0; vt < 3; ++vt) {
          f16x8 va = *(const f16x8*)&Vc[(vt * 32 + l32) * 72 + s * 16 + h * 8];
          o[0][vt] = mfma_f16_32(va, pv[0], o[0][vt]);
          o[1][vt] = mfma_f16_32(va, pv[1], o[1][vt]);
        }
      }
    }
  }

  // epilogue: rowsum = vdim-80 row = o[qt][2] reg 8 on h=0 lanes
#pragma unroll
  for (int qt = 0; qt < 2; ++qt) {
    float rsum = __shfl(o[qt][2][8], l32);
    float inv = 1.0f / rsum;
    int s = q0 + w * 64 + qt * 32 + l32;
    float* rowT = outT + ((size_t)bb * NS + s) * HT + hh * 64 + 4 * h;
#pragma unroll
    for (int vt = 0; vt < 2; ++vt)
#pragma unroll
      for (int g = 0; g < 4; ++g) {
        float4 v4;
        v4.x = o[qt][vt][4 * g + 0] * inv; v4.y = o[qt][vt][4 * g + 1] * inv;
        v4.z = o[qt][vt][4 * g + 2] * inv; v4.w = o[qt][vt][4 * g + 3] * inv;
        *(float4*)(rowT + vt * 32 + 8 * g) = v4;
      }
    float* rowL = outL + ((size_t)bb * NS + s) * HL + hh * 16 + 4 * h;
#pragma unroll
    for (int g = 0; g < 2; ++g) {
      float4 v4;
      v4.x = o[qt][2][4 * g + 0] * inv; v4.y = o[qt][2][4 * g + 1] * inv;
      v4.z = o[qt][2][4 * g + 2] * inv; v4.w = o[qt][2][4 * g + 3] * inv;
      *(float4*)(rowL + 8 * g) = v4;
    }
  }
}

extern "C" void kernel_launch(void* const* d_in, const int* in_sizes, int n_in,
                              void* d_out, int out_size, void* d_ws, size_t ws_size,
                              hipStream_t stream) {
  const float* hs  = (const float*)d_in[0];
  const float* li  = (const float*)d_in[1];
  const float* Wq  = (const float*)d_in[2];
  const float* bq  = (const float*)d_in[3];
  const float* Wk  = (const float*)d_in[4];
  const float* bk  = (const float*)d_in[5];
  const float* Wv  = (const float*)d_in[6];
  const float* bv  = (const float*)d_in[7];
  const float* lWq = (const float*)d_in[8];
  const float* lbq = (const float*)d_in[9];
  const float* lWk = (const float*)d_in[10];
  const float* lbk = (const float*)d_in[11];
  const float* lWv = (const float*)d_in[12];
  const float* lbv = (const float*)d_in[13];

  char* ws = (char*)d_ws;
  size_t off = 0;
  auto alloc = [&](size_t bytes) {
    char* p = ws + off;
    off += (bytes + 255) & ~(size_t)255;
    return (unsigned short*)p;
  };
  unsigned short* Xb   = alloc((size_t)8192 * 768 * 2);
  unsigned short* Xlb  = alloc((size_t)8192 * 192 * 2);
  unsigned short* WtQ  = alloc((size_t)768 * 768 * 2);
  unsigned short* WtK  = alloc((size_t)768 * 768 * 2);
  unsigned short* WtV  = alloc((size_t)768 * 768 * 2);
  unsigned short* WtLQ = alloc((size_t)192 * 192 * 2);
  unsigned short* WtLK = alloc((size_t)192 * 192 * 2);
  unsigned short* WtLV = alloc((size_t)192 * 192 * 2);
  unsigned short* Qs   = alloc((size_t)NB * NHH * NS * DH * 2);
  unsigned short* Ks   = alloc((size_t)NB * NHH * NS * DH * 2);
  unsigned short* Vs   = alloc((size_t)NB * NHH * NS * DH * 2 + 256);

  // 1) prep: casts + coalesced tiled transposes
  k_prep<<<9516, 256, 0, stream>>>(hs, li, Wq, Wk, Wv, lWq, lWk, lWv,
                                   Xb, Xlb, WtQ, WtK, WtV, WtLQ, WtLK, WtLV);

  const float LOG2E = 1.4426950408889634f;
  const float s8 = 0.35355339059327373f;  // 1/sqrt(8): text q,k each
  const float s4 = 0.5f;                  // 1/sqrt(4): layout q,k each
  // 2) text QKV, 128x128 tiles (Q carries log2e for exp2 softmax)
  {
    ProjArgs pa;
    pa.Wt[0] = WtQ; pa.Wt[1] = WtK; pa.Wt[2] = WtV;
    pa.bias[0] = bq; pa.bias[1] = bk; pa.bias[2] = bv;
    pa.dst[0] = Qs; pa.dst[1] = Ks; pa.dst[2] = Vs;
    pa.scale[0] = s8 * LOG2E; pa.scale[1] = s8; pa.scale[2] = 1.f;
    pa.mode[0] = 0; pa.mode[1] = 0; pa.mode[2] = 1;
    k_proj<8><<<dim3(64, 6, 3), 256, 0, stream>>>(Xb, pa, 768, 6, 0);
  }
  // 3) layout QKV, 128x64 tiles
  {
    ProjArgs pa;
    pa.Wt[0] = WtLQ; pa.Wt[1] = WtLK; pa.Wt[2] = WtLV;
    pa.bias[0] = lbq; pa.bias[1] = lbk; pa.bias[2] = lbv;
    pa.dst[0] = Qs; pa.dst[1] = Ks; pa.dst[2] = Vs;
    pa.scale[0] = s4 * LOG2E; pa.scale[1] = s4; pa.scale[2] = 1.f;
    pa.mode[0] = 0; pa.mode[1] = 0; pa.mode[2] = 1;
    k_proj<4><<<dim3(64, 3, 3), 256, 0, stream>>>(Xlb, pa, 192, 4, 64);
  }
  // 4) fused two-stream attention (x = head for XCD L2 locality, y = q-block)
  float* outT = (float*)d_out;
  float* outL = outT + (size_t)NB * NS * HT;
  k_attn<<<dim3(48, 16), 128, 0, stream>>>(Qs, Ks, Vs, outT, outL);
}

// Round 9
// 240.852 us; speedup vs baseline: 1.5732x; 1.5732x over previous
//
#include <hip/hip_runtime.h>
#include <cstdint>
#include <cstddef>

#define NB 4
#define NS 2048
#define NHH 12
#define DH 80      // concatenated head dim (64 text + 16 layout)
#define HT 768
#define HL 192

typedef __bf16 bf16x8 __attribute__((ext_vector_type(8)));
typedef _Float16 f16x8 __attribute__((ext_vector_type(8)));
typedef _Float16 f16x2 __attribute__((ext_vector_type(2)));
typedef float f32x4 __attribute__((ext_vector_type(4)));
typedef float f32x16 __attribute__((ext_vector_type(16)));
typedef unsigned short u16x4 __attribute__((ext_vector_type(4)));

__device__ __forceinline__ unsigned short bfc(float f) {
  __bf16 b = (__bf16)f;
  return __builtin_bit_cast(unsigned short, b);
}
__device__ __forceinline__ unsigned short f16c(float f) {
  _Float16 h = (_Float16)f;
  return __builtin_bit_cast(unsigned short, h);
}

__device__ __forceinline__ float ex2(float x) {
  return __builtin_amdgcn_exp2f(x);   // raw v_exp_f32 (base-2)
}

__device__ __forceinline__ f32x4 mfma_bf16_k32(bf16x8 a, bf16x8 b, f32x4 c) {
  return __builtin_amdgcn_mfma_f32_16x16x32_bf16(a, b, c, 0, 0, 0);
}
__device__ __forceinline__ f32x16 mfma_bf16_32(bf16x8 a, bf16x8 b, f32x16 c) {
  return __builtin_amdgcn_mfma_f32_32x32x16_bf16(a, b, c, 0, 0, 0);
}
__device__ __forceinline__ f32x16 mfma_f16_32(f16x8 a, f16x8 b, f32x16 c) {
  return __builtin_amdgcn_mfma_f32_32x32x16_f16(a, b, c, 0, 0, 0);
}

__device__ __forceinline__ f16x2 pk_f16(float a, float b) {
  return __builtin_bit_cast(f16x2, __builtin_amdgcn_cvt_pkrtz(a, b));
}

// async global->LDS, 16B per lane (LDS dst must be wave-uniform base + lane*16)
__device__ __forceinline__ void gl_lds(const unsigned short* g, unsigned short* l) {
  __builtin_amdgcn_global_load_lds(
      (const __attribute__((address_space(1))) uint32_t*)g,
      (__attribute__((address_space(3))) uint32_t*)l, 16, 0, 0);
}

// ---------------- prep: fp32->bf16 casts + LDS-tiled weight transposes -------
__global__ __launch_bounds__(256) void k_prep(
    const float* __restrict__ hs, const float* __restrict__ li,
    const float* __restrict__ Wq, const float* __restrict__ Wk, const float* __restrict__ Wv,
    const float* __restrict__ lWq, const float* __restrict__ lWk, const float* __restrict__ lWv,
    unsigned short* __restrict__ Xb, unsigned short* __restrict__ Xlb,
    unsigned short* __restrict__ WtQ, unsigned short* __restrict__ WtK,
    unsigned short* __restrict__ WtV, unsigned short* __restrict__ WtLQ,
    unsigned short* __restrict__ WtLK, unsigned short* __restrict__ WtLV) {
  __shared__ float Ts[32][33];
  int blk = blockIdx.x, tid = threadIdx.x;
  if (blk < 7680) {  // casts, 4 floats/thread, coalesced float4
    const float* src; unsigned short* dst; int i;
    if (blk < 6144) { src = hs; dst = Xb;  i = blk * 256 + tid; }
    else            { src = li; dst = Xlb; i = (blk - 6144) * 256 + tid; }
    float4 v = *(const float4*)(src + (size_t)i * 4);
    u16x4 o; o[0] = bfc(v.x); o[1] = bfc(v.y); o[2] = bfc(v.z); o[3] = bfc(v.w);
    *(u16x4*)(dst + (size_t)i * 4) = o;
  } else {           // tiled transpose: wt[n*K+k] = w[k*K+n] (square)
    const float* w; unsigned short* wt; int t, K;
    if (blk < 9408) {
      int b2 = blk - 7680; int m = b2 / 576; t = b2 - m * 576; K = 768;
      w  = (m == 0) ? Wq  : (m == 1) ? Wk  : Wv;
      wt = (m == 0) ? WtQ : (m == 1) ? WtK : WtV;
    } else {
      int b2 = blk - 9408; int m = b2 / 36; t = b2 - m * 36; K = 192;
      w  = (m == 0) ? lWq  : (m == 1) ? lWk  : lWv;
      wt = (m == 0) ? WtLQ : (m == 1) ? WtLK : WtLV;
    }
    int TB = K >> 5;                 // tiles per dim
    int kb = t / TB, nb = t - kb * TB;
    int tx = tid & 31, ty = tid >> 5;
#pragma unroll
    for (int j = 0; j < 4; ++j)
      Ts[ty + j * 8][tx] = w[(size_t)(kb * 32 + ty + j * 8) * K + nb * 32 + tx];
    __syncthreads();
#pragma unroll
    for (int j = 0; j < 4; ++j)
      wt[(size_t)(nb * 32 + ty + j * 8) * K + kb * 32 + tx] = bfc(Ts[tx][ty + j * 8]);
  }
}

// ---------------- fused QKV projection (blockIdx.z = 0:Q 1:K 2:V) -----------
// R6-benched version: non-swapped MFMA, mode-0 scalar epilogue. Do not "optimize"
// the store pattern here without counters: the R8 swapped/u16x4 variant caused
// 7.6x HBM write amplification + evicted X from L2/L3 (FETCH 234 MB, 190 us).
struct ProjArgs {
  const unsigned short* Wt[3];
  const float* bias[3];
  unsigned short* dst[3];
  float scale[3];
  int mode[3];   // 0: q/k bf16 layout [b,h,s,80], 1: v f16 transposed [b,h,80,s]
};

template<int NT>   // BN = NT*16 output cols per block; BM=128, BK=64
__global__ __launch_bounds__(256, 4) void k_proj(
    const unsigned short* __restrict__ Xb, ProjArgs pa,
    int K, int hdshift, int dofs) {
  constexpr int BN = NT * 16;
  __shared__ unsigned short Xs[128 * 72];
  __shared__ unsigned short Ws[BN * 72];
  int z = blockIdx.z;
  const unsigned short* Wt = pa.Wt[z];
  int m0 = blockIdx.x * 128, n0 = blockIdx.y * BN;
  int tid = threadIdx.x;
  int lane = tid & 63, wave = tid >> 6, quad = lane >> 4, l16 = lane & 15;

  f32x4 acc[2][NT];
#pragma unroll
  for (int mt = 0; mt < 2; ++mt)
#pragma unroll
    for (int nt = 0; nt < NT; ++nt) {
      acc[mt][nt][0] = 0.f; acc[mt][nt][1] = 0.f;
      acc[mt][nt][2] = 0.f; acc[mt][nt][3] = 0.f;
    }

  for (int kk = 0; kk < K; kk += 64) {
    constexpr int XCH = 128 * 9;   // 16B chunks (9/row: 8 data + 1 pad)
#pragma unroll
    for (int p = 0; p < (XCH + 255) / 256; ++p) {
      int i = p * 256 + tid;
      if (i < XCH) {
        int r = i / 9, c = i - r * 9;
        gl_lds(Xb + (size_t)(m0 + r) * K + kk + (c == 8 ? 0 : c * 8), Xs + i * 8);
      }
    }
    constexpr int WCH = BN * 9;
#pragma unroll
    for (int p = 0; p < (WCH + 255) / 256; ++p) {
      int i = p * 256 + tid;
      if (i < WCH) {
        int r = i / 9, c = i - r * 9;
        gl_lds(Wt + (size_t)(n0 + r) * K + kk + (c == 8 ? 0 : c * 8), Ws + i * 8);
      }
    }
    __syncthreads();

#pragma unroll
    for (int kc = 0; kc < 2; ++kc) {
      bf16x8 a0 = *(const bf16x8*)&Xs[(wave * 32 + l16) * 72 + kc * 32 + quad * 8];
      bf16x8 a1 = *(const bf16x8*)&Xs[(wave * 32 + 16 + l16) * 72 + kc * 32 + quad * 8];
#pragma unroll
      for (int nt = 0; nt < NT; ++nt) {
        bf16x8 b = *(const bf16x8*)&Ws[(nt * 16 + l16) * 72 + kc * 32 + quad * 8];
        acc[0][nt] = mfma_bf16_k32(a0, b, acc[0][nt]);
        acc[1][nt] = mfma_bf16_k32(a1, b, acc[1][nt]);
      }
    }
    __syncthreads();
  }

  const float* bias = pa.bias[z];
  unsigned short* dst = pa.dst[z];
  float scale = pa.scale[z];
  int mode = pa.mode[z];
  int hdm = (1 << hdshift) - 1;
#pragma unroll
  for (int mt = 0; mt < 2; ++mt) {
#pragma unroll
    for (int nt = 0; nt < NT; ++nt) {
      int n = n0 + nt * 16 + l16;
      float bv = bias[n];
      int mbase = m0 + wave * 32 + mt * 16 + quad * 4;
      int h = n >> hdshift, d = n & hdm;
      if (mode == 0) {
#pragma unroll
        for (int r = 0; r < 4; ++r) {
          int m = mbase + r;
          int b = m >> 11, s = m & (NS - 1);
          dst[((size_t)(b * NHH + h) * NS + s) * DH + dofs + d] =
              bfc((acc[mt][nt][r] + bv) * scale);
        }
      } else {
        int b = mbase >> 11, s = mbase & (NS - 1);
        u16x4 pk;
#pragma unroll
        for (int r = 0; r < 4; ++r) pk[r] = f16c((acc[mt][nt][r] + bv) * scale);
        *(u16x4*)(dst + ((size_t)(b * NHH + h) * DH + dofs + d) * NS + s) = pk;
      }
    }
  }
}

// ---------------- fused two-stream attention, 32x32 MFMA, 64q/wave ----------
// Q',K' [b,h,s,80] bf16 pre-scaled (Q carries log2e); V' [b,h,80,s] f16.
// 128 queries/block, 2 waves x 64 queries (2 col-tiles), 64-key tiles,
// double-buffered staging, one barrier/tile. K stored with key bits2<->3
// swapped so Sc^T C-regs 8p..8p+7 ARE the PV B-frag for key-step 2t+p.
// K/V LDS frags shared across each wave's 2 query tiles (halves LDS reads).
// Rowsum via ones-row 80 of V'. Grid (48,16): head-major -> XCD L2 locality.
__global__ __launch_bounds__(128, 2) void k_attn(
    const unsigned short* __restrict__ Qg, const unsigned short* __restrict__ Kg,
    const unsigned short* __restrict__ Vg,
    float* __restrict__ outT, float* __restrict__ outL) {
  __shared__ unsigned short KT[2][64 * 88];   // stride 88 shorts (11 chunks/row)
  __shared__ unsigned short VT[2][96 * 72];   // stride 72 shorts (9 chunks/row)

  int tid = threadIdx.x;
  int lane = tid & 63, w = tid >> 6, h = lane >> 5, l32 = lane & 31;
  int bh = blockIdx.x, qb = blockIdx.y;
  int bb = bh / NHH, hh = bh - bb * NHH;
  int q0 = qb * 128;

  const unsigned short* kg0 = Kg + (size_t)bh * NS * DH;
  const unsigned short* vg0 = Vg + (size_t)bh * DH * NS;

  // ones row 80 (f16 1.0) + zero rows 81..95, both buffers
  for (int i = tid; i < 2304; i += 128) {
    int b = i / 1152, j = i - b * 1152;
    VT[b][80 * 72 + j] = (j < 72) ? (unsigned short)0x3C00 : (unsigned short)0;
  }

  // Q B-frags: qf[qt][kc][j] = Q[q0 + w*64 + qt*32 + l32][kc*16 + 8h + j]
  bf16x8 qf[2][5];
#pragma unroll
  for (int qt = 0; qt < 2; ++qt) {
    const unsigned short* qrow =
        Qg + ((size_t)bh * NS + q0 + w * 64 + qt * 32 + l32) * DH;
#pragma unroll
    for (int kc = 0; kc < 5; ++kc)
      qf[qt][kc] = *(const bf16x8*)(qrow + kc * 16 + h * 8);
  }

  f32x16 o[2][3];
#pragma unroll
  for (int qt = 0; qt < 2; ++qt)
#pragma unroll
    for (int vt = 0; vt < 3; ++vt)
#pragma unroll
      for (int r = 0; r < 16; ++r) o[qt][vt][r] = 0.f;

  auto stage = [&](int buf, int kt) {
    const unsigned short* kb = kg0 + (size_t)kt * 64 * DH;
    unsigned short* dk = &KT[buf][0];
#pragma unroll
    for (int p = 0; p < 6; ++p) {           // 64 rows x 11 chunks = 704
      int i = p * 128 + tid;
      if (i < 704) {
        int r = i / 11, c = i - r * 11;
        int rs = ((((r >> 2) ^ (r >> 3)) & 1) ? (r ^ 12) : r);  // swap key bits 2,3
        gl_lds(kb + (size_t)rs * DH + (c == 10 ? 0 : c * 8), dk + i * 8);
      }
    }
    int k0 = kt * 64;
    unsigned short* dv = &VT[buf][0];
#pragma unroll
    for (int p = 0; p < 6; ++p) {           // 80 rows x 9 chunks = 720
      int i = p * 128 + tid;
      if (i < 720) {
        int r = i / 9, c = i - r * 9;
        gl_lds((c == 8) ? vg0 : (vg0 + (size_t)r * NS + k0 + c * 8), dv + i * 8);
      }
    }
  };

  stage(0, 0);

  for (int kt = 0; kt < 32; ++kt) {
    int cur = kt & 1;
    __syncthreads();                 // drains tile-kt loads; frees other buffer
    if (kt + 1 < 32) stage(cur ^ 1, kt + 1);

    const unsigned short* Kc = &KT[cur][0];
    const unsigned short* Vc = &VT[cur][0];

    // Sc^T: 2 key-tiles x 2 query-tiles, K-dim 80 = 5 steps of 16.
    // K A-frag shared across the 2 query tiles.
    f32x16 st[2][2];
#pragma unroll
    for (int qt = 0; qt < 2; ++qt)
#pragma unroll
      for (int t = 0; t < 2; ++t)
#pragma unroll
        for (int r = 0; r < 16; ++r) st[qt][t][r] = 0.f;

#pragma unroll
    for (int kc = 0; kc < 5; ++kc) {
#pragma unroll
      for (int t = 0; t < 2; ++t) {
        bf16x8 a = *(const bf16x8*)&Kc[(t * 32 + l32) * 88 + kc * 16 + h * 8];
        st[0][t] = mfma_bf16_32(a, qf[0][kc], st[0][t]);
        st[1][t] = mfma_bf16_32(a, qf[1][kc], st[1][t]);
      }
    }

    // exp2 + pack (Q pre-scaled by log2e); V A-frag shared across query tiles
#pragma unroll
    for (int t = 0; t < 2; ++t) {
#pragma unroll
      for (int p = 0; p < 2; ++p) {
        f16x8 pv[2];
#pragma unroll
        for (int qt = 0; qt < 2; ++qt) {
          union { f16x8 v; f16x2 h2[4]; } u;
#pragma unroll
          for (int j2 = 0; j2 < 4; ++j2)
            u.h2[j2] = pk_f16(ex2(st[qt][t][8 * p + 2 * j2]),
                              ex2(st[qt][t][8 * p + 2 * j2 + 1]));
          pv[qt] = u.v;
        }
        int s = 2 * t + p;
#pragma unroll
        for (int vt = 0; vt < 3; ++vt) {
          f16x8 va = *(const f16x8*)&Vc[(vt * 32 + l32) * 72 + s * 16 + h * 8];
          o[0][vt] = mfma_f16_32(va, pv[0], o[0][vt]);
          o[1][vt] = mfma_f16_32(va, pv[1], o[1][vt]);
        }
      }
    }
  }

  // epilogue: rowsum = vdim-80 row = o[qt][2] reg 8 on h=0 lanes
#pragma unroll
  for (int qt = 0; qt < 2; ++qt) {
    float rsum = __shfl(o[qt][2][8], l32);
    float inv = 1.0f / rsum;
    int s = q0 + w * 64 + qt * 32 + l32;
    float* rowT = outT + ((size_t)bb * NS + s) * HT + hh * 64 + 4 * h;
#pragma unroll
    for (int vt = 0; vt < 2; ++vt)
#pragma unroll
      for (int g = 0; g < 4; ++g) {
        float4 v4;
        v4.x = o[qt][vt][4 * g + 0] * inv; v4.y = o[qt][vt][4 * g + 1] * inv;
        v4.z = o[qt][vt][4 * g + 2] * inv; v4.w = o[qt][vt][4 * g + 3] * inv;
        *(float4*)(rowT + vt * 32 + 8 * g) = v4;
      }
    float* rowL = outL + ((size_t)bb * NS + s) * HL + hh * 16 + 4 * h;
#pragma unroll
    for (int g = 0; g < 2; ++g) {
      float4 v4;
      v4.x = o[qt][2][4 * g + 0] * inv; v4.y = o[qt][2][4 * g + 1] * inv;
      v4.z = o[qt][2][4 * g + 2] * inv; v4.w = o[qt][2][4 * g + 3] * inv;
      *(float4*)(rowL + 8 * g) = v4;
    }
  }
}

extern "C" void kernel_launch(void* const* d_in, const int* in_sizes, int n_in,
                              void* d_out, int out_size, void* d_ws, size_t ws_size,
                              hipStream_t stream) {
  const float* hs  = (const float*)d_in[0];
  const float* li  = (const float*)d_in[1];
  const float* Wq  = (const float*)d_in[2];
  const float* bq  = (const float*)d_in[3];
  const float* Wk  = (const float*)d_in[4];
  const float* bk  = (const float*)d_in[5];
  const float* Wv  = (const float*)d_in[6];
  const float* bv  = (const float*)d_in[7];
  const float* lWq = (const float*)d_in[8];
  const float* lbq = (const float*)d_in[9];
  const float* lWk = (const float*)d_in[10];
  const float* lbk = (const float*)d_in[11];
  const float* lWv = (const float*)d_in[12];
  const float* lbv = (const float*)d_in[13];

  char* ws = (char*)d_ws;
  size_t off = 0;
  auto alloc = [&](size_t bytes) {
    char* p = ws + off;
    off += (bytes + 255) & ~(size_t)255;
    return (unsigned short*)p;
  };
  unsigned short* Xb   = alloc((size_t)8192 * 768 * 2);
  unsigned short* Xlb  = alloc((size_t)8192 * 192 * 2);
  unsigned short* WtQ  = alloc((size_t)768 * 768 * 2);
  unsigned short* WtK  = alloc((size_t)768 * 768 * 2);
  unsigned short* WtV  = alloc((size_t)768 * 768 * 2);
  unsigned short* WtLQ = alloc((size_t)192 * 192 * 2);
  unsigned short* WtLK = alloc((size_t)192 * 192 * 2);
  unsigned short* WtLV = alloc((size_t)192 * 192 * 2);
  unsigned short* Qs   = alloc((size_t)NB * NHH * NS * DH * 2);
  unsigned short* Ks   = alloc((size_t)NB * NHH * NS * DH * 2);
  unsigned short* Vs   = alloc((size_t)NB * NHH * NS * DH * 2 + 256);

  // 1) prep: casts + coalesced tiled transposes
  k_prep<<<9516, 256, 0, stream>>>(hs, li, Wq, Wk, Wv, lWq, lWk, lWv,
                                   Xb, Xlb, WtQ, WtK, WtV, WtLQ, WtLK, WtLV);

  const float LOG2E = 1.4426950408889634f;
  const float s8 = 0.35355339059327373f;  // 1/sqrt(8): text q,k each
  const float s4 = 0.5f;                  // 1/sqrt(4): layout q,k each
  // 2) text QKV, 128x128 tiles (Q carries log2e for exp2 softmax)
  {
    ProjArgs pa;
    pa.Wt[0] = WtQ; pa.Wt[1] = WtK; pa.Wt[2] = WtV;
    pa.bias[0] = bq; pa.bias[1] = bk; pa.bias[2] = bv;
    pa.dst[0] = Qs; pa.dst[1] = Ks; pa.dst[2] = Vs;
    pa.scale[0] = s8 * LOG2E; pa.scale[1] = s8; pa.scale[2] = 1.f;
    pa.mode[0] = 0; pa.mode[1] = 0; pa.mode[2] = 1;
    k_proj<8><<<dim3(64, 6, 3), 256, 0, stream>>>(Xb, pa, 768, 6, 0);
  }
  // 3) layout QKV, 128x64 tiles
  {
    ProjArgs pa;
    pa.Wt[0] = WtLQ; pa.Wt[1] = WtLK; pa.Wt[2] = WtLV;
    pa.bias[0] = lbq; pa.bias[1] = lbk; pa.bias[2] = lbv;
    pa.dst[0] = Qs; pa.dst[1] = Ks; pa.dst[2] = Vs;
    pa.scale[0] = s4 * LOG2E; pa.scale[1] = s4; pa.scale[2] = 1.f;
    pa.mode[0] = 0; pa.mode[1] = 0; pa.mode[2] = 1;
    k_proj<4><<<dim3(64, 3, 3), 256, 0, stream>>>(Xlb, pa, 192, 4, 64);
  }
  // 4) fused two-stream attention (x = head for XCD L2 locality, y = q-block)
  float* outT = (float*)d_out;
  float* outL = outT + (size_t)NB * NS * HT;
  k_attn<<<dim3(48, 16), 128, 0, stream>>>(Qs, Ks, Vs, outT, outL);
}